// Round 3
// baseline (2198.721 us; speedup 1.0000x reference)
//
#include <hip/hip_runtime.h>
#include <hip/hip_bf16.h>
#include <math.h>

#define N_NODES 50000
#define E_EDGES 800000
#define ET (E_EDGES + N_NODES)
#define IN_DIM 3000
#define HID 512
#define LAT 30
#define XH_STRIDE 32
#define NEG_SLOPE 0.2f
#define KPAD 3072
#define ENC_NT 94   // ceil(3000/32)

typedef __bf16 bfv8 __attribute__((ext_vector_type(8)));
typedef float f32x4 __attribute__((ext_vector_type(4)));

__device__ __forceinline__ float eluf(float x) { return x > 0.f ? x : expm1f(x); }

__device__ __forceinline__ unsigned fkey(float f) {
    unsigned u = __float_as_uint(f);
    return (u & 0x80000000u) ? ~u : (u | 0x80000000u);
}
__device__ __forceinline__ float funkey(unsigned k) {
    unsigned u = (k & 0x80000000u) ? (k ^ 0x80000000u) : ~k;
    return __uint_as_float(u);
}

__global__ void k_init(float* __restrict__ zbuf, unsigned* __restrict__ amax, float* __restrict__ denom) {
    int gid = blockIdx.x * 256 + threadIdx.x;
    if (gid < N_NODES * XH_STRIDE) zbuf[gid] = 0.f;
    if (gid < N_NODES) { amax[gid] = 0u; denom[gid] = 0.f; }
}

__global__ void k_transpose_w(const float* __restrict__ w, float* __restrict__ wt) {
    int idx = blockIdx.x * 256 + threadIdx.x;
    if (idx < HID * LAT) {
        int j = idx / LAT, c = idx % LAT;
        wt[c * HID + j] = w[idx];
    }
}

// enc_w1 [512][3000] f32 -> w1b [512][3072] bf16 (K-padded) and w1bt [3072][512] bf16 (transposed)
__global__ void k_conv_w(const float* __restrict__ w, __bf16* __restrict__ w1b, __bf16* __restrict__ w1bt) {
    int idx = blockIdx.x * 256 + threadIdx.x;
    if (idx >= HID * KPAD) return;
    int j = idx / KPAD, k = idx - j * KPAD;
    float v = (k < IN_DIM) ? w[(size_t)j * IN_DIM + k] : 0.f;
    __bf16 b = (__bf16)v;
    w1b[(size_t)j * KPAD + k] = b;
    w1bt[(size_t)k * HID + j] = b;
}

// ================= Encoder GEMM: h = elu(x @ enc_w1^T + b) =================
// M=50000, N=512(full per block), K=3000. BM=128, BK=32, 512 threads (8 waves 2x4).
// LDS k-slot-major layouts -> conflict-free ds_read_b128 / ds_write_b128.
__global__ __launch_bounds__(512, 2)
void k_enc_gemm(const float* __restrict__ A, const __bf16* __restrict__ Bb,
                const float* __restrict__ bias, float* __restrict__ C) {
    __shared__ __bf16 As[2][4 * 128 * 8];   // [buf][(ks*128+row)*8]
    __shared__ __bf16 Bs[2][4 * 512 * 8];   // [buf][(ks*512+col)*8]
    const int tid = threadIdx.x;
    const int lane = tid & 63, wv = tid >> 6;
    const int wr = wv >> 2, wc = wv & 3;
    const int l16 = lane & 15, lh = lane >> 4;
    const int i0 = blockIdx.x * 128;

    // A-stage mapping: thread -> (row, kslot)
    const int arow = tid & 127, aks = tid >> 7;
    int asrc_row = i0 + arow; if (asrc_row >= N_NODES) asrc_row = N_NODES - 1;
    const float* ap = A + (size_t)asrc_row * IN_DIM + aks * 8;

    f32x4 acc[4][8] = {};
    float4 a0, a1;

    auto stageB = [&](int kt, int b) {
#pragma unroll
        for (int is = 0; is < 4; ++is) {
            int g = wv * 4 + is;                       // 0..31
            const __bf16* src = Bb + (size_t)((g & 7) * 64 + lane) * KPAD + kt + (g >> 3) * 8;
            __builtin_amdgcn_global_load_lds(
                (const __attribute__((address_space(1))) void*)src,
                (__attribute__((address_space(3))) void*)(&Bs[b][(size_t)g * 512]),
                16, 0, 0);
        }
    };
    auto loadA = [&](int kt) {
        a0 = make_float4(0.f, 0.f, 0.f, 0.f);
        a1 = make_float4(0.f, 0.f, 0.f, 0.f);
        if (kt + aks * 8 < IN_DIM) {                   // IN_DIM % 8 == 0: chunk all-valid or all-pad
            const float4* p = (const float4*)(ap + kt);
            a0 = p[0]; a1 = p[1];
        }
    };
    auto writeA = [&](int b) {
        bfv8 pk;
        pk[0] = (__bf16)a0.x; pk[1] = (__bf16)a0.y; pk[2] = (__bf16)a0.z; pk[3] = (__bf16)a0.w;
        pk[4] = (__bf16)a1.x; pk[5] = (__bf16)a1.y; pk[6] = (__bf16)a1.z; pk[7] = (__bf16)a1.w;
        *(bfv8*)&As[b][((size_t)aks * 128 + arow) * 8] = pk;
    };

    // prologue: stage tile 0
    stageB(0, 0);
    loadA(0);
    writeA(0);
    asm volatile("s_waitcnt vmcnt(0)" ::: "memory");
    __syncthreads();

    int cur = 0;
    for (int t = 0; t < ENC_NT; ++t) {
        bool has_next = (t + 1) < ENC_NT;
        if (has_next) {
            stageB((t + 1) * 32, cur ^ 1);
            loadA((t + 1) * 32);
        }
        bfv8 af[4], bfr[8];
#pragma unroll
        for (int mi = 0; mi < 4; ++mi)
            af[mi] = *(const bfv8*)&As[cur][((size_t)lh * 128 + wr * 64 + mi * 16 + l16) * 8];
#pragma unroll
        for (int ni = 0; ni < 8; ++ni)
            bfr[ni] = *(const bfv8*)&Bs[cur][((size_t)lh * 512 + wc * 128 + ni * 16 + l16) * 8];
#pragma unroll
        for (int mi = 0; mi < 4; ++mi)
#pragma unroll
            for (int ni = 0; ni < 8; ++ni)
                acc[mi][ni] = __builtin_amdgcn_mfma_f32_16x16x32_bf16(af[mi], bfr[ni], acc[mi][ni], 0, 0, 0);
        if (has_next) writeA(cur ^ 1);
        asm volatile("s_waitcnt vmcnt(0)" ::: "memory");
        __syncthreads();
        cur ^= 1;
    }

    // epilogue: C/D layout col=lane&15, row=(lane>>4)*4+reg
#pragma unroll
    for (int ni = 0; ni < 8; ++ni) {
        int col = wc * 128 + ni * 16 + l16;
        float bv = bias[col];
#pragma unroll
        for (int mi = 0; mi < 4; ++mi) {
            int row0 = i0 + wr * 64 + mi * 16 + lh * 4;
#pragma unroll
            for (int r = 0; r < 4; ++r) {
                int row = row0 + r;
                if (row < N_NODES)
                    C[(size_t)row * HID + col] = eluf(acc[mi][ni][r] + bv);
            }
        }
    }
}

// ================= Decoder GEMM: x_recon = hd @ enc_w1 + dec_b2 =================
// M=50000, N=3000, K=512. BM=64, 256 threads (4 waves, each 64 cols/chunk).
// A-panel (64x512 bf16 = 64KB) staged once via global_load_lds; B streamed from L2.
__global__ __launch_bounds__(256, 2)
void k_dec_gemm(const __bf16* __restrict__ hdb, const __bf16* __restrict__ Bt,
                const float* __restrict__ bias, float* __restrict__ C) {
    __shared__ __bf16 As[64 * 64 * 8];   // [(kc*64+row)*8], kc = k/8 (0..63)
    const int tid = threadIdx.x;
    const int lane = tid & 63, wv = tid >> 6;
    const int l16 = lane & 15, lh = lane >> 4;
    const int i0 = blockIdx.x * 64;

    // stage A panel: 64 issue-groups, group g covers kc=g, row=lane
#pragma unroll
    for (int is = 0; is < 16; ++is) {
        int g = wv * 16 + is;                          // 0..63
        int row = i0 + lane; if (row >= N_NODES) row = N_NODES - 1;
        const __bf16* src = hdb + (size_t)row * HID + g * 8;
        __builtin_amdgcn_global_load_lds(
            (const __attribute__((address_space(1))) void*)src,
            (__attribute__((address_space(3))) void*)(&As[(size_t)g * 512]),
            16, 0, 0);
    }
    asm volatile("s_waitcnt vmcnt(0)" ::: "memory");
    __syncthreads();

    for (int cc = 0; cc < 12; ++cc) {
        int c0 = cc * 256 + wv * 64;
        f32x4 acc[4][4] = {};
#pragma unroll
        for (int ks = 0; ks < 16; ++ks) {
            bfv8 af[4], bfr[4];
#pragma unroll
            for (int ni = 0; ni < 4; ++ni)
                bfr[ni] = *(const bfv8*)(Bt + (size_t)(c0 + ni * 16 + l16) * HID + ks * 32 + lh * 8);
#pragma unroll
            for (int mi = 0; mi < 4; ++mi)
                af[mi] = *(const bfv8*)&As[((size_t)(ks * 4 + lh) * 64 + mi * 16 + l16) * 8];
#pragma unroll
            for (int mi = 0; mi < 4; ++mi)
#pragma unroll
                for (int ni = 0; ni < 4; ++ni)
                    acc[mi][ni] = __builtin_amdgcn_mfma_f32_16x16x32_bf16(af[mi], bfr[ni], acc[mi][ni], 0, 0, 0);
        }
#pragma unroll
        for (int ni = 0; ni < 4; ++ni) {
            int col = c0 + ni * 16 + l16;
            if (col >= IN_DIM) continue;
            float bv = bias[col];
#pragma unroll
            for (int mi = 0; mi < 4; ++mi) {
                int row0 = i0 + mi * 16 + lh * 4;
#pragma unroll
                for (int r = 0; r < 4; ++r) {
                    int row = row0 + r;
                    if (row < N_NODES)
                        C[(size_t)row * IN_DIM + col] = acc[mi][ni][r] + bv;
                }
            }
        }
    }
}

// xh = h @ gat_w ; si/sj = att dots. 32 nodes per block.
__global__ __launch_bounds__(256)
void k_gat_proj(const float* __restrict__ h, const float* __restrict__ gat_w,
                const float* __restrict__ gat_att,
                float* __restrict__ xh, float* __restrict__ si, float* __restrict__ sj) {
    __shared__ float gwl[HID * LAT];
    __shared__ float atl[2 * LAT];
    int tid = threadIdx.x;
    for (int i = tid; i < HID * LAT; i += 256) gwl[i] = gat_w[i];
    if (tid < 2 * LAT) atl[tid] = gat_att[tid];
    __syncthreads();
    int c = tid & 31;
    bool act = c < LAT;
    for (int it = 0; it < 4; ++it) {
        int n = blockIdx.x * 32 + it * 8 + (tid >> 5);
        if (n >= N_NODES) continue;
        float accv = 0.f;
        const float4* h4 = (const float4*)(h + (size_t)n * HID);
#pragma unroll 4
        for (int j4 = 0; j4 < HID / 4; ++j4) {
            float4 hv = h4[j4];
            if (act) {
                int b = j4 * 4 * LAT + c;
                accv = fmaf(hv.x, gwl[b], accv);
                accv = fmaf(hv.y, gwl[b + LAT], accv);
                accv = fmaf(hv.z, gwl[b + 2 * LAT], accv);
                accv = fmaf(hv.w, gwl[b + 3 * LAT], accv);
            }
        }
        float xhv = act ? accv : 0.f;
        xh[(size_t)n * XH_STRIDE + c] = xhv;
        float sip = act ? atl[c] * xhv : 0.f;
        float sjp = act ? atl[LAT + c] * xhv : 0.f;
#pragma unroll
        for (int off = 16; off > 0; off >>= 1) {
            sip += __shfl_down(sip, off, 32);
            sjp += __shfl_down(sjp, off, 32);
        }
        if (c == 0) { si[n] = sip; sj[n] = sjp; }
    }
}

__global__ void k_edge_alpha(const int* __restrict__ ei, const float* __restrict__ eattr,
                             const float* __restrict__ si, const float* __restrict__ sj,
                             float* __restrict__ alphaE, unsigned* __restrict__ amax) {
    int e = blockIdx.x * 256 + threadIdx.x;
    if (e >= ET) return;
    int s, d; float w;
    if (e < E_EDGES) { s = ei[e]; d = ei[E_EDGES + e]; w = eattr[e]; }
    else { s = d = e - E_EDGES; w = 1.f; }
    float a = si[d] + sj[s];
    a = a >= 0.f ? a : NEG_SLOPE * a;
    a *= w;
    alphaE[e] = a;
    atomicMax(&amax[d], fkey(a));
}

// merged: alpha_hat = exp(alpha - amax[d]); denom += alpha_hat; zbuf += alpha_hat * xh[s]
__global__ void k_edge_expscatter(const int* __restrict__ ei, const float* __restrict__ alphaE,
                                  const unsigned* __restrict__ amax, float* __restrict__ denom,
                                  const float* __restrict__ xh, float* __restrict__ zbuf) {
    int gid = blockIdx.x * 256 + threadIdx.x;
    int e = gid >> 5, c = gid & 31;
    if (e >= ET) return;
    int s, d;
    if (e < E_EDGES) { s = ei[e]; d = ei[E_EDGES + e]; }
    else { s = d = e - E_EDGES; }
    float v = expf(alphaE[e] - funkey(amax[d]));
    if (c == 0) atomicAdd(&denom[d], v);
    if (c < LAT) atomicAdd(&zbuf[(size_t)d * XH_STRIDE + c], v * xh[(size_t)s * XH_STRIDE + c]);
}

// z = elu(zbuf/denom + gat_b); also writes zout
__global__ void k_z(const float* __restrict__ gat_b, const float* __restrict__ denom,
                    float* __restrict__ zbuf, float* __restrict__ zout) {
    int gid = blockIdx.x * 256 + threadIdx.x;
    int n = gid >> 5, c = gid & 31;
    if (n >= N_NODES) return;
    if (c < LAT) {
        float v = eluf(zbuf[gid] / (denom[n] + 1e-16f) + gat_b[c]);
        zbuf[gid] = v;
        zout[(size_t)n * LAT + c] = v;
    }
}

// hd[i,j] = elu( sum_c z[i,c]*dec_w1[j,c] + dec_b1[j] ) -> bf16
__global__ __launch_bounds__(256)
void k_dec1(const float* __restrict__ zbuf, const float* __restrict__ wt,
            const float* __restrict__ b, __bf16* __restrict__ hdb) {
    int gid = blockIdx.x * 256 + threadIdx.x;
    if (gid >= N_NODES * HID) return;
    int j = gid & (HID - 1);
    size_t i = (size_t)(gid >> 9);
    float acc = b[j];
#pragma unroll
    for (int c = 0; c < LAT; ++c)
        acc = fmaf(zbuf[i * XH_STRIDE + c], wt[c * HID + j], acc);
    hdb[gid] = (__bf16)eluf(acc);
}

extern "C" void kernel_launch(void* const* d_in, const int* in_sizes, int n_in,
                              void* d_out, int out_size, void* d_ws, size_t ws_size,
                              hipStream_t stream) {
    const float* x      = (const float*)d_in[0];
    const int*   ei     = (const int*)d_in[1];
    const float* eattr  = (const float*)d_in[2];
    const float* enc_w1 = (const float*)d_in[3];
    const float* enc_b1 = (const float*)d_in[4];
    const float* gat_w  = (const float*)d_in[5];
    const float* gat_att= (const float*)d_in[6];
    const float* gat_b  = (const float*)d_in[7];
    const float* dec_w1 = (const float*)d_in[8];
    const float* dec_b1 = (const float*)d_in[9];
    const float* dec_b2 = (const float*)d_in[10];

    float* out  = (float*)d_out;
    float* xrec = out;
    float* zout = out + (size_t)N_NODES * IN_DIM;

    float* ws = (float*)d_ws;
    float*    h      = ws;                         // 25,600,000 f32 (h; later hdb bf16 aliases front)
    float*    xh     = ws + 25600000;              //  1,600,000
    float*    zbuf   = ws + 27200000;              //  1,600,000
    float*    si     = ws + 28800000;
    float*    sj     = ws + 28850000;
    unsigned* amax   = (unsigned*)(ws + 28900000);
    float*    denom  = ws + 28950000;
    float*    alphaE = ws + 29000000;
    float*    wt     = ws + 29850000;
    __bf16*   w1b    = (__bf16*)(ws + 29865360);   // 512*3072 bf16
    __bf16*   w1bt   = (__bf16*)(ws + 30651792);   // 3072*512 bf16
    __bf16*   hdb    = (__bf16*)h;                 // 50000*512 bf16, aliases h (h dead by then)

    (void)in_sizes; (void)n_in; (void)out_size; (void)ws_size;

    k_init<<<(N_NODES * XH_STRIDE + 255) / 256, 256, 0, stream>>>(zbuf, amax, denom);
    k_transpose_w<<<(HID * LAT + 255) / 256, 256, 0, stream>>>(dec_w1, wt);
    k_conv_w<<<(HID * KPAD + 255) / 256, 256, 0, stream>>>(enc_w1, w1b, w1bt);

    k_enc_gemm<<<(N_NODES + 127) / 128, 512, 0, stream>>>(x, w1b, enc_b1, h);

    k_gat_proj<<<(N_NODES + 31) / 32, 256, 0, stream>>>(h, gat_w, gat_att, xh, si, sj);
    k_edge_alpha<<<(ET + 255) / 256, 256, 0, stream>>>(ei, eattr, si, sj, alphaE, amax);
    k_edge_expscatter<<<((size_t)ET * 32 + 255) / 256, 256, 0, stream>>>(ei, alphaE, amax, denom, xh, zbuf);
    k_z<<<(N_NODES * 32 + 255) / 256, 256, 0, stream>>>(gat_b, denom, zbuf, zout);
    k_dec1<<<(N_NODES * HID + 255) / 256, 256, 0, stream>>>(zbuf, wt, dec_b1, hdb);

    k_dec_gemm<<<(N_NODES + 63) / 64, 256, 0, stream>>>(hdb, w1bt, dec_b2, xrec);
}

// Round 5
// 1788.192 us; speedup vs baseline: 1.2296x; 1.2296x over previous
//
#include <hip/hip_runtime.h>
#include <hip/hip_bf16.h>
#include <math.h>

#define N_NODES 50000
#define E_EDGES 800000
#define ET (E_EDGES + N_NODES)
#define IN_DIM 3000
#define HID 512
#define LAT 30
#define XH_STRIDE 32
#define NEG_SLOPE 0.2f
#define KPAD 3072
#define ENC_NT 94   // ceil(3000/32)
#define APITCH 40   // padded A-row pitch in bf16 elems (80B, 16B-aligned)

typedef __bf16 bfv8 __attribute__((ext_vector_type(8)));
typedef float f32x4 __attribute__((ext_vector_type(4)));

__device__ __forceinline__ float eluf(float x) { return x > 0.f ? x : expm1f(x); }

__device__ __forceinline__ unsigned fkey(float f) {
    unsigned u = __float_as_uint(f);
    return (u & 0x80000000u) ? ~u : (u | 0x80000000u);
}
__device__ __forceinline__ float funkey(unsigned k) {
    unsigned u = (k & 0x80000000u) ? (k ^ 0x80000000u) : ~k;
    return __uint_as_float(u);
}

__global__ void k_init(float* __restrict__ zbuf, unsigned* __restrict__ amax, float* __restrict__ denom) {
    int gid = blockIdx.x * 256 + threadIdx.x;
    if (gid < N_NODES * XH_STRIDE) zbuf[gid] = 0.f;
    if (gid < N_NODES) { amax[gid] = 0u; denom[gid] = 0.f; }
}

__global__ void k_transpose_w(const float* __restrict__ w, float* __restrict__ wt) {
    int idx = blockIdx.x * 256 + threadIdx.x;
    if (idx < HID * LAT) {
        int j = idx / LAT, c = idx % LAT;
        wt[c * HID + j] = w[idx];
    }
}

// enc_w1 [512][3000] f32 -> w1b [512][3072] bf16 (K-padded) and w1bt [3072][512] bf16 (transposed)
__global__ void k_conv_w(const float* __restrict__ w, __bf16* __restrict__ w1b, __bf16* __restrict__ w1bt) {
    int idx = blockIdx.x * 256 + threadIdx.x;
    if (idx >= HID * KPAD) return;
    int j = idx / KPAD, k = idx - j * KPAD;
    float v = (k < IN_DIM) ? w[(size_t)j * IN_DIM + k] : 0.f;
    __bf16 b = (__bf16)v;
    w1b[(size_t)j * KPAD + k] = b;
    w1bt[(size_t)k * HID + j] = b;
}

// ============ Encoder GEMM: h = elu(x @ enc_w1^T + b), M=50000 N=512 K=3000 ============
__global__ __launch_bounds__(256)
void k_enc_gemm(const float* __restrict__ A, const __bf16* __restrict__ Bb,
                const float* __restrict__ bias, float* __restrict__ C) {
    __shared__ __bf16 As[2][128 * APITCH];
    __shared__ __bf16 Bs[2][4096];
    const int tid = threadIdx.x;
    const int lane = tid & 63, wv = tid >> 6;
    const int wr = wv >> 1, wc = wv & 1;
    const int l16 = lane & 15, lh = lane >> 4;
    const int i0 = blockIdx.y * 128;
    const int c0 = blockIdx.x * 128;

    const int arow = tid >> 2, akc = tid & 3;
    const float* apA = A + (size_t)(i0 + arow) * IN_DIM + akc * 8;   // rows < 50048 -> row 0..49983 valid
    const int r1 = i0 + arow + 64;
    const float* apB = A + (size_t)(r1 < N_NODES ? r1 : N_NODES - 1) * IN_DIM + akc * 8;

    f32x4 acc[4][4] = {};
    float4 a00, a01, a10, a11;

    auto stageB = [&](int kt, int b) {
#pragma unroll
        for (int s = 0; s < 2; ++s) {
            int g = wv * 2 + s;
            int col = (g & 1) * 64 + lane, ks = g >> 1;
            const __bf16* src = Bb + (size_t)(c0 + col) * KPAD + kt + ks * 8;
            __builtin_amdgcn_global_load_lds(
                (const __attribute__((address_space(1))) void*)src,
                (__attribute__((address_space(3))) void*)(&Bs[b][(size_t)g * 512]),
                16, 0, 0);
        }
    };
    auto loadA = [&](int kt) {
        a00 = a01 = a10 = a11 = make_float4(0.f, 0.f, 0.f, 0.f);
        if (kt + akc * 8 < IN_DIM) {
            const float4* p0 = (const float4*)(apA + kt);
            a00 = p0[0]; a01 = p0[1];
            const float4* p1 = (const float4*)(apB + kt);
            a10 = p1[0]; a11 = p1[1];
        }
    };
    auto writeA = [&](int b) {
        bfv8 pk;
        pk[0] = (__bf16)a00.x; pk[1] = (__bf16)a00.y; pk[2] = (__bf16)a00.z; pk[3] = (__bf16)a00.w;
        pk[4] = (__bf16)a01.x; pk[5] = (__bf16)a01.y; pk[6] = (__bf16)a01.z; pk[7] = (__bf16)a01.w;
        *(bfv8*)&As[b][(size_t)arow * APITCH + akc * 8] = pk;
        pk[0] = (__bf16)a10.x; pk[1] = (__bf16)a10.y; pk[2] = (__bf16)a10.z; pk[3] = (__bf16)a10.w;
        pk[4] = (__bf16)a11.x; pk[5] = (__bf16)a11.y; pk[6] = (__bf16)a11.z; pk[7] = (__bf16)a11.w;
        *(bfv8*)&As[b][(size_t)(arow + 64) * APITCH + akc * 8] = pk;
    };

    stageB(0, 0);
    loadA(0);
    writeA(0);
    asm volatile("s_waitcnt vmcnt(0)" ::: "memory");   // gll-LDS publish: vmcnt tracked, compiler can't see it
    __syncthreads();

    int cur = 0;
    for (int t = 0; t < ENC_NT; ++t) {
        bool nxt = (t + 1) < ENC_NT;
        if (nxt) {
            stageB((t + 1) * 32, cur ^ 1);
            loadA((t + 1) * 32);
        }
        bfv8 af[4], bfr[4];
#pragma unroll
        for (int mi = 0; mi < 4; ++mi)
            af[mi] = *(const bfv8*)&As[cur][(size_t)(wr * 64 + mi * 16 + l16) * APITCH + lh * 8];
#pragma unroll
        for (int ni = 0; ni < 4; ++ni)
            bfr[ni] = *(const bfv8*)&Bs[cur][((size_t)lh * 128 + wc * 64 + ni * 16 + l16) * 8];
#pragma unroll
        for (int mi = 0; mi < 4; ++mi)
#pragma unroll
            for (int ni = 0; ni < 4; ++ni)
                acc[mi][ni] = __builtin_amdgcn_mfma_f32_16x16x32_bf16(af[mi], bfr[ni], acc[mi][ni], 0, 0, 0);
        if (nxt) writeA(cur ^ 1);
        asm volatile("s_waitcnt vmcnt(0)" ::: "memory");
        __syncthreads();
        cur ^= 1;
    }

    // C/D layout: col = lane&15, row = (lane>>4)*4 + reg
#pragma unroll
    for (int ni = 0; ni < 4; ++ni) {
        int col = c0 + wc * 64 + ni * 16 + l16;
        float bv = bias[col];
#pragma unroll
        for (int mi = 0; mi < 4; ++mi) {
            int row0 = i0 + wr * 64 + mi * 16 + lh * 4;
#pragma unroll
            for (int r = 0; r < 4; ++r) {
                int row = row0 + r;
                if (row < N_NODES)
                    C[(size_t)row * HID + col] = eluf(acc[mi][ni][r] + bv);
            }
        }
    }
}

// ============ Decoder GEMM: x_recon = hd @ enc_w1 + dec_b2, M=50000 N=3000 K=512 ============
__global__ __launch_bounds__(256)
void k_dec_gemm(const __bf16* __restrict__ Ab, const __bf16* __restrict__ Bt,
                const float* __restrict__ bias, float* __restrict__ C) {
    __shared__ __bf16 As[2][4096];
    __shared__ __bf16 Bs[2][4096];
    const int tid = threadIdx.x;
    const int lane = tid & 63, wv = tid >> 6;
    const int wr = wv >> 1, wc = wv & 1;
    const int l16 = lane & 15, lh = lane >> 4;
    const int i0 = blockIdx.y * 128;
    const int c0 = blockIdx.x * 128;

    f32x4 acc[4][4] = {};

    auto stage = [&](int kt, int b) {
#pragma unroll
        for (int s = 0; s < 2; ++s) {
            int g = wv * 2 + s;
            int rc = (g & 1) * 64 + lane, ks = g >> 1;
            int row = i0 + rc; if (row >= N_NODES) row = N_NODES - 1;
            const __bf16* srcA = Ab + (size_t)row * HID + kt + ks * 8;
            __builtin_amdgcn_global_load_lds(
                (const __attribute__((address_space(1))) void*)srcA,
                (__attribute__((address_space(3))) void*)(&As[b][(size_t)g * 512]),
                16, 0, 0);
            const __bf16* srcB = Bt + (size_t)(c0 + rc) * HID + kt + ks * 8;
            __builtin_amdgcn_global_load_lds(
                (const __attribute__((address_space(1))) void*)srcB,
                (__attribute__((address_space(3))) void*)(&Bs[b][(size_t)g * 512]),
                16, 0, 0);
        }
    };

    stage(0, 0);
    asm volatile("s_waitcnt vmcnt(0)" ::: "memory");
    __syncthreads();

    int cur = 0;
#pragma unroll 1
    for (int t = 0; t < 16; ++t) {
        if (t < 15) stage((t + 1) * 32, cur ^ 1);
        bfv8 af[4], bfr[4];
#pragma unroll
        for (int mi = 0; mi < 4; ++mi)
            af[mi] = *(const bfv8*)&As[cur][((size_t)lh * 128 + wr * 64 + mi * 16 + l16) * 8];
#pragma unroll
        for (int ni = 0; ni < 4; ++ni)
            bfr[ni] = *(const bfv8*)&Bs[cur][((size_t)lh * 128 + wc * 64 + ni * 16 + l16) * 8];
#pragma unroll
        for (int mi = 0; mi < 4; ++mi)
#pragma unroll
            for (int ni = 0; ni < 4; ++ni)
                acc[mi][ni] = __builtin_amdgcn_mfma_f32_16x16x32_bf16(af[mi], bfr[ni], acc[mi][ni], 0, 0, 0);
        asm volatile("s_waitcnt vmcnt(0)" ::: "memory");
        __syncthreads();
        cur ^= 1;
    }

#pragma unroll
    for (int ni = 0; ni < 4; ++ni) {
        int col = c0 + wc * 64 + ni * 16 + l16;
        if (col >= IN_DIM) continue;
        float bv = bias[col];
#pragma unroll
        for (int mi = 0; mi < 4; ++mi) {
            int row0 = i0 + wr * 64 + mi * 16 + lh * 4;
#pragma unroll
            for (int r = 0; r < 4; ++r) {
                int row = row0 + r;
                if (row < N_NODES)
                    C[(size_t)row * IN_DIM + col] = acc[mi][ni][r] + bv;
            }
        }
    }
}

// xh = h @ gat_w ; si/sj = att dots. 128 nodes per block.
__global__ __launch_bounds__(256)
void k_gat_proj(const float* __restrict__ h, const float* __restrict__ gat_w,
                const float* __restrict__ gat_att,
                float* __restrict__ xh, float* __restrict__ si, float* __restrict__ sj) {
    __shared__ float gwl[HID * LAT];
    __shared__ float atl[2 * LAT];
    int tid = threadIdx.x;
    for (int i = tid; i < HID * LAT; i += 256) gwl[i] = gat_w[i];
    if (tid < 2 * LAT) atl[tid] = gat_att[tid];
    __syncthreads();
    int c = tid & 31;
    bool act = c < LAT;
    for (int it = 0; it < 16; ++it) {
        int n = blockIdx.x * 128 + it * 8 + (tid >> 5);
        if (n >= N_NODES) continue;
        float accv = 0.f;
        const float4* h4 = (const float4*)(h + (size_t)n * HID);
#pragma unroll 4
        for (int j4 = 0; j4 < HID / 4; ++j4) {
            float4 hv = h4[j4];
            if (act) {
                int b = j4 * 4 * LAT + c;
                accv = fmaf(hv.x, gwl[b], accv);
                accv = fmaf(hv.y, gwl[b + LAT], accv);
                accv = fmaf(hv.z, gwl[b + 2 * LAT], accv);
                accv = fmaf(hv.w, gwl[b + 3 * LAT], accv);
            }
        }
        float xhv = act ? accv : 0.f;
        xh[(size_t)n * XH_STRIDE + c] = xhv;
        float sip = act ? atl[c] * xhv : 0.f;
        float sjp = act ? atl[LAT + c] * xhv : 0.f;
#pragma unroll
        for (int off = 16; off > 0; off >>= 1) {
            sip += __shfl_down(sip, off, 32);
            sjp += __shfl_down(sjp, off, 32);
        }
        if (c == 0) { si[n] = sip; sj[n] = sjp; }
    }
}

__global__ void k_edge_alpha(const int* __restrict__ ei, const float* __restrict__ eattr,
                             const float* __restrict__ si, const float* __restrict__ sj,
                             float* __restrict__ alphaE, unsigned* __restrict__ amax) {
    int e = blockIdx.x * 256 + threadIdx.x;
    if (e >= ET) return;
    int s, d; float w;
    if (e < E_EDGES) { s = ei[e]; d = ei[E_EDGES + e]; w = eattr[e]; }
    else { s = d = e - E_EDGES; w = 1.f; }
    float a = si[d] + sj[s];
    a = a >= 0.f ? a : NEG_SLOPE * a;
    a *= w;
    alphaE[e] = a;
    atomicMax(&amax[d], fkey(a));
}

// one thread per edge: v = exp(a - amax[d]); alphaE[e] = v; denom[d] += v
__global__ void k_edge_exp(const int* __restrict__ ei, float* __restrict__ alphaE,
                           const unsigned* __restrict__ amax, float* __restrict__ denom) {
    int e = blockIdx.x * 256 + threadIdx.x;
    if (e >= ET) return;
    int d = (e < E_EDGES) ? ei[E_EDGES + e] : (e - E_EDGES);
    float v = expf(alphaE[e] - funkey(amax[d]));
    alphaE[e] = v;
    atomicAdd(&denom[d], v);
}

// 32 lanes per edge: zbuf[d,:] += v * xh[s,:]
__global__ void k_edge_scatter(const int* __restrict__ ei, const float* __restrict__ alphaE,
                               const float* __restrict__ xh, float* __restrict__ zbuf) {
    int gid = blockIdx.x * 256 + threadIdx.x;
    int e = gid >> 5, c = gid & 31;
    if (e >= ET || c >= LAT) return;
    int s, d;
    if (e < E_EDGES) { s = ei[e]; d = ei[E_EDGES + e]; }
    else { s = d = e - E_EDGES; }
    atomicAdd(&zbuf[(size_t)d * XH_STRIDE + c], alphaE[e] * xh[(size_t)s * XH_STRIDE + c]);
}

// z = elu(zbuf/denom + gat_b); also writes zout
__global__ void k_z(const float* __restrict__ gat_b, const float* __restrict__ denom,
                    float* __restrict__ zbuf, float* __restrict__ zout) {
    int gid = blockIdx.x * 256 + threadIdx.x;
    int n = gid >> 5, c = gid & 31;
    if (n >= N_NODES) return;
    if (c < LAT) {
        float v = eluf(zbuf[gid] / (denom[n] + 1e-16f) + gat_b[c]);
        zbuf[gid] = v;
        zout[(size_t)n * LAT + c] = v;
    }
}

// hd[i,j] = elu( sum_c z[i,c]*dec_w1[j,c] + dec_b1[j] ) -> bf16
__global__ __launch_bounds__(256)
void k_dec1(const float* __restrict__ zbuf, const float* __restrict__ wt,
            const float* __restrict__ b, __bf16* __restrict__ hdb) {
    int gid = blockIdx.x * 256 + threadIdx.x;
    if (gid >= N_NODES * HID) return;
    int j = gid & (HID - 1);
    size_t i = (size_t)(gid >> 9);
    float acc = b[j];
#pragma unroll
    for (int c = 0; c < LAT; ++c)
        acc = fmaf(zbuf[i * XH_STRIDE + c], wt[c * HID + j], acc);
    hdb[gid] = (__bf16)eluf(acc);
}

extern "C" void kernel_launch(void* const* d_in, const int* in_sizes, int n_in,
                              void* d_out, int out_size, void* d_ws, size_t ws_size,
                              hipStream_t stream) {
    const float* x      = (const float*)d_in[0];
    const int*   ei     = (const int*)d_in[1];
    const float* eattr  = (const float*)d_in[2];
    const float* enc_w1 = (const float*)d_in[3];
    const float* enc_b1 = (const float*)d_in[4];
    const float* gat_w  = (const float*)d_in[5];
    const float* gat_att= (const float*)d_in[6];
    const float* gat_b  = (const float*)d_in[7];
    const float* dec_w1 = (const float*)d_in[8];
    const float* dec_b1 = (const float*)d_in[9];
    const float* dec_b2 = (const float*)d_in[10];

    float* out  = (float*)d_out;
    float* xrec = out;
    float* zout = out + (size_t)N_NODES * IN_DIM;

    float* ws = (float*)d_ws;
    float*    h      = ws;                         // 25,600,000 f32 (h; later hdb bf16 aliases front)
    float*    xh     = ws + 25600000;              //  1,600,000
    float*    zbuf   = ws + 27200000;              //  1,600,000
    float*    si     = ws + 28800000;
    float*    sj     = ws + 28850000;
    unsigned* amax   = (unsigned*)(ws + 28900000);
    float*    denom  = ws + 28950000;
    float*    alphaE = ws + 29000000;
    float*    wt     = ws + 29850000;
    __bf16*   w1b    = (__bf16*)(ws + 29865360);   // 512*3072 bf16
    __bf16*   w1bt   = (__bf16*)(ws + 30651792);   // 3072*512 bf16
    __bf16*   hdb    = (__bf16*)h;                 // 50000*512 bf16, aliases h (h dead by then)

    (void)in_sizes; (void)n_in; (void)out_size; (void)ws_size;

    k_init<<<(N_NODES * XH_STRIDE + 255) / 256, 256, 0, stream>>>(zbuf, amax, denom);
    k_transpose_w<<<(HID * LAT + 255) / 256, 256, 0, stream>>>(dec_w1, wt);
    k_conv_w<<<(HID * KPAD + 255) / 256, 256, 0, stream>>>(enc_w1, w1b, w1bt);

    {
        dim3 g(HID / 128, (N_NODES + 127) / 128);          // (4, 391), x-fastest: A-panel reuse
        k_enc_gemm<<<g, 256, 0, stream>>>(x, w1b, enc_b1, h);
    }

    k_gat_proj<<<(N_NODES + 127) / 128, 256, 0, stream>>>(h, gat_w, gat_att, xh, si, sj);
    k_edge_alpha<<<(ET + 255) / 256, 256, 0, stream>>>(ei, eattr, si, sj, alphaE, amax);
    k_edge_exp<<<(ET + 255) / 256, 256, 0, stream>>>(ei, alphaE, amax, denom);
    k_edge_scatter<<<((size_t)ET * 32 + 255) / 256, 256, 0, stream>>>(ei, alphaE, xh, zbuf);
    k_z<<<(N_NODES * 32 + 255) / 256, 256, 0, stream>>>(gat_b, denom, zbuf, zout);
    k_dec1<<<(N_NODES * HID + 255) / 256, 256, 0, stream>>>(zbuf, wt, dec_b1, hdb);

    {
        dim3 g(KPAD / 128, (N_NODES + 127) / 128);         // (24, 391)
        k_dec_gemm<<<g, 256, 0, stream>>>(hdb, w1bt, dec_b2, xrec);
    }
}